// Round 11
// baseline (293.376 us; speedup 1.0000x reference)
//
#include <hip/hip_runtime.h>

constexpr int W    = 96;
constexpr int NPIX = 9216;
constexpr int NPK  = 18;          // 72 channels = 18 float4 packs (DC, cos1..35, sin1..35, pad)
constexpr int NM   = 35;
constexpr int TB   = 384;
constexpr int RPS  = 24;          // rows per stripe
constexpr int PPS  = RPS*W;       // 2304 px per stripe

constexpr float LCLIP = 18.420681f;   // -log(1e-8)

// ---- init: Fourier basis tables, pixel-major packs (libm-accurate, as in R10) ----
__global__ __launch_bounds__(256) void k_init(const float* __restrict__ img,
                                              float4* __restrict__ Bsplat,
                                              float4* __restrict__ Bslice){
    int px = blockIdx.x*256 + threadIdx.x;
    if (px >= NPIX) return;
    float th = img[px] * 0.0122718463f;            // 2*pi/512
    float sp[72], sl[72];
    sp[0] = 0.6923648f;  sl[0] = 1.f;              // DC: 10*sqrt(400*pi)/512 (compat 10 folded)
    #pragma unroll
    for (int m = 1; m <= NM; ++m){
        float s, c;
        sincosf((float)m*th, &s, &c);              // libm: accurate reduction
        float A = 1.3847296f * __expf(-0.0150598f*(float)(m*m));
        sp[m]    = A*c;  sl[m]    = c;             // cos channels 1..35
        sp[NM+m] = A*s;  sl[NM+m] = s;             // sin channels 36..70
    }
    sp[71] = 0.f; sl[71] = 0.f;                    // pad channel
    float4* dsp = Bsplat + (size_t)px*NPK;
    float4* dsl = Bslice + (size_t)px*NPK;
    #pragma unroll
    for (int pk = 0; pk < NPK; ++pk){
        dsp[pk] = make_float4(sp[4*pk], sp[4*pk+1], sp[4*pk+2], sp[4*pk+3]);
        dsl[pk] = make_float4(sl[4*pk], sl[4*pk+1], sl[4*pk+2], sl[4*pk+3]);
    }
}

// ---- one launch = one mean-field iteration; block = one output column X ----
// MODE 0: q0 from mask; grid 192 (blocks 96..191 run the ones-pipeline -> ksum).
// MODE 1: reconstruct q_t from msgprev; write msg_t.
// MODE 2: reconstruct q4; compute msg4 and the final argmax directly.
template<int MODE>
__global__ __launch_bounds__(TB) void k_it(
        const int* __restrict__ mask,
        const float4* __restrict__ Bsplat, const float4* __restrict__ Bslice,
        const float* __restrict__ msgprev, float* __restrict__ msgcur,
        float* __restrict__ ksum,
        const float* __restrict__ qprev, float* __restrict__ qcur,
        float* __restrict__ out)
{
    __shared__ float4 UN[96*19];     // phase A/C: qs rows (padded 97); phase D/E: V4
    __shared__ float4 H4[96*19];     // H-conv result [y][pk]
    __shared__ float  w50[96], w3t[96], t50v[192], t3v[192], H3[96], V3[96], qcol[96];

    const int  t    = threadIdx.x;
    const bool ONES = (MODE==0) && (blockIdx.x >= 96);
    const int  X    = blockIdx.x % 96;
    float* qs = (float*)UN;          // [RPS][97] padded rows

    if (t < 96){
        float d = (float)(X - t);
        w50[t] = __expf(-d*d*(1.f/5000.f));        // bilateral spatial taps vs own col
        w3t[t] = __expf(-d*d*(1.f/18.f));          // sxy=3 gaussian taps vs own col
    } else if (t < 288){
        int i = t - 96;                            // 0..191: d = i-96
        float d = (float)(i - 96);
        t50v[i] = __expf(-d*d*(1.f/5000.f));
        t3v[i]  = __expf(-d*d*(1.f/18.f));
    }

    // ---- stripes: A (recon q rows) + C (H-conv rows) ----
    for (int s = 0; s < 4; ++s){
        __syncthreads();                           // tables ready / qs reusable
        #pragma unroll
        for (int k = 0; k < PPS/TB; ++k){          // 6 px per thread
            int l  = t + k*TB;
            int px = s*PPS + l;
            float q;
            if (ONES){
                q = 1.f;
            } else if (MODE == 0){
                float duv = (mask[px]==0) ? LCLIP : -LCLIP;
                q = 1.f/(1.f+__expf(duv));
            } else {
                float duv = (mask[px]==0) ? LCLIP : -LCLIP;
                float delta = duv + ksum[px] - 2.f*(msgprev[px] - 13.f*qprev[px]);
                q = 1.f/(1.f+__expf(delta));
            }
            int yl = l/96, xx = l - yl*96;
            qs[yl*97 + xx] = q;
            if (!ONES){
                if (blockIdx.x == 0) qcur[px] = q;   // designated writer (next iter's diag)
                if (xx == X) qcol[s*RPS + yl] = q;   // own column's q (final diag)
            }
        }
        __syncthreads();
        // H-conv for this stripe: tasks (row, pk) ; pk==18 -> sxy=3 channel
        for (int tau = t; tau < RPS*19; tau += TB){
            int yl = tau/19, pk = tau - yl*19;
            int y  = s*RPS + yl;
            const float* qrow = qs + yl*97;
            if (pk < 18){
                const float4* brow = Bsplat + ((size_t)y*96)*NPK + pk;
                float4 a = make_float4(0.f,0.f,0.f,0.f);
                #pragma unroll 8
                for (int xp = 0; xp < 96; ++xp){
                    float  qw = qrow[xp]*w50[xp];
                    float4 b  = brow[(size_t)xp*NPK];
                    a.x = fmaf(qw,b.x,a.x); a.y = fmaf(qw,b.y,a.y);
                    a.z = fmaf(qw,b.z,a.z); a.w = fmaf(qw,b.w,a.w);
                }
                H4[y*19+pk] = a;
            } else {
                float h = 0.f;
                #pragma unroll 8
                for (int xp = 0; xp < 96; ++xp) h = fmaf(qrow[xp], w3t[xp], h);
                H3[y] = h;
            }
        }
    }
    __syncthreads();       // H4/H3 complete; qs dead -> UN becomes V4

    // ---- phase D: V-conv (6-row register tiles), threads 288+ do the sxy=3 channel ----
    if (t < 288){
        int h = t/18, pk = t - h*18;
        int y0 = 6*h;
        float4 a[6];
        #pragma unroll
        for (int i = 0; i < 6; ++i) a[i] = make_float4(0.f,0.f,0.f,0.f);
        for (int yp = 0; yp < 96; ++yp){
            float4 v = H4[yp*19+pk];
            #pragma unroll
            for (int i = 0; i < 6; ++i){
                float wv = t50v[y0+i-yp+96];
                a[i].x = fmaf(wv,v.x,a[i].x); a[i].y = fmaf(wv,v.y,a[i].y);
                a[i].z = fmaf(wv,v.z,a[i].z); a[i].w = fmaf(wv,v.w,a[i].w);
            }
        }
        #pragma unroll
        for (int i = 0; i < 6; ++i) UN[(y0+i)*19+pk] = a[i];
    } else if (t < 384){
        int y = t - 288;
        float v = 0.f;
        for (int yp = 0; yp < 96; ++yp) v = fmaf(H3[yp], t3v[y-yp+96], v);
        V3[y] = v;
    }
    __syncthreads();

    // ---- phase E: slice (f64 dot) + store / final ----
    if (t < 96){
        int y = t, px = y*96 + X;
        const float4* bs = Bslice + (size_t)px*NPK;
        double acc = 0.0;
        #pragma unroll
        for (int pk = 0; pk < 18; ++pk){
            float4 v = UN[y*19+pk];
            float4 b = bs[pk];
            acc += (double)v.x*b.x + (double)v.y*b.y + (double)v.z*b.z + (double)v.w*b.w;
        }
        float msgv = (float)acc + 3.f*V3[y];       // bilateral (compat 10 folded) + gaussian
        if (ONES){
            ksum[px] = msgv - 13.f;                // column sum of K, diagonal removed
        } else if (MODE == 2){
            float duv = (mask[px]==0) ? LCLIP : -LCLIP;
            float delta = duv + ksum[px] - 2.f*(msgv - 13.f*qcol[y]);
            out[px] = (delta > 0.f) ? 1.f : 0.f;   // argmax; tie -> label 0
        } else {
            msgcur[px] = msgv;
        }
    }
}

extern "C" void kernel_launch(void* const* d_in, const int* in_sizes, int n_in,
                              void* d_out, int out_size, void* d_ws, size_t ws_size,
                              hipStream_t stream){
    const float* img  = (const float*)d_in[0];
    const int*   mask = (const int*)d_in[1];
    float* out = (float*)d_out;
    float* ws  = (float*)d_ws;

    constexpr size_t TBL = (size_t)NPIX*NPK*4;     // floats per basis table
    float4* Bsp  = (float4*)ws;
    float4* Bsl  = (float4*)(ws + TBL);
    float*  base = ws + 2*TBL;
    float* msgA = base;
    float* msgB = base + NPIX;
    float* qA   = base + 2*NPIX;
    float* qB   = base + 3*NPIX;
    float* ksum = base + 4*NPIX;

    k_init<<<dim3(36), dim3(256), 0, stream>>>(img, Bsp, Bsl);
    // iter 0: msg0 = K q0 (blocks 0-95) and ksum = K 1 (blocks 96-191)
    k_it<0><<<dim3(192), dim3(TB), 0, stream>>>(mask, Bsp, Bsl, msgB, msgA, ksum, qB, qA, out);
    // iters 1..3
    k_it<1><<<dim3(96), dim3(TB), 0, stream>>>(mask, Bsp, Bsl, msgA, msgB, ksum, qA, qB, out);
    k_it<1><<<dim3(96), dim3(TB), 0, stream>>>(mask, Bsp, Bsl, msgB, msgA, ksum, qB, qA, out);
    k_it<1><<<dim3(96), dim3(TB), 0, stream>>>(mask, Bsp, Bsl, msgA, msgB, ksum, qA, qB, out);
    // iter 4 + final update (iteration 5) + argmax, fused
    k_it<2><<<dim3(96), dim3(TB), 0, stream>>>(mask, Bsp, Bsl, msgB, msgA, ksum, qB, qA, out);
}